// Round 6
// baseline (2246.675 us; speedup 1.0000x reference)
//
#include <hip/hip_runtime.h>
#include <cmath>

typedef float f32x4 __attribute__((ext_vector_type(4)));
typedef short short8 __attribute__((ext_vector_type(8)));

#define N_POINTS 524288
#define TMASK 0x7FFFFu   // T_MAX-1, hashed levels all have size 2^19
#define NCELLS 32768     // 32^3 Morton cells
#define TILES  4         // points tiles per block (pipeline depth)

struct HashCfg { int res[16]; int off[16]; unsigned hashed_mask; int total; };

// ---- ws layout (bytes) ----
#define S0_OFF   0
#define S1_OFF   1024
#define S2_OFF   2048
#define W2L_OFF  3328
#define B0_OFF   4608
#define B1_OFF   (B0_OFF + 49152)
#define B2_OFF   (B1_OFF + 131072)
#define TBF_OFF  (B2_OFF + 131072)   // bf16x2 table copy (~24.5 MB); sort arrays after

__device__ inline unsigned short f2bf(float f){
  unsigned u = __float_as_uint(f);
  u = (u + 0x7FFFu + ((u >> 16) & 1u)) >> 16;
  return (unsigned short)u;
}
__device__ inline float bf2f(unsigned short h){
  return __uint_as_float(((unsigned)h) << 16);
}
__device__ inline float softplus100_fast(float x){
  float y = 100.f * x;
  return 0.01f * (fmaxf(y, 0.f) + __logf(1.f + __expf(-fabsf(y))));
}
__device__ inline unsigned morton5(unsigned cx, unsigned cy, unsigned cz){
  unsigned k = 0;
  #pragma unroll
  for (int b = 0; b < 5; b++){
    k |= ((cx >> b) & 1u) << (3*b)
       | ((cy >> b) & 1u) << (3*b + 1)
       | ((cz >> b) & 1u) << (3*b + 2);
  }
  return k;
}

// ---- precompute 1: weight-norm row scales ----
__global__ void scale_kernel(const float* __restrict__ v0, const float* __restrict__ g0,
                             const float* __restrict__ v1, const float* __restrict__ g1,
                             const float* __restrict__ v2, const float* __restrict__ g2,
                             char* __restrict__ ws){
  int r = blockIdx.x * 256 + threadIdx.x;
  if (r < 256){
    float s = 0.f;
    for (int k = 0; k < 71; k++){ float t = v0[r*71+k]; s += t*t; }
    ((float*)(ws + S0_OFF))[r] = g0[r] / sqrtf(s);
  } else if (r < 512){
    int o = r - 256; float s = 0.f;
    for (int k = 0; k < 256; k++){ float t = v1[o*256+k]; s += t*t; }
    ((float*)(ws + S1_OFF))[o] = g1[o] / sqrtf(s);
  } else if (r < 769){
    int o = r - 512; float s = 0.f;
    for (int k = 0; k < 256; k++){ float t = v2[o*256+k]; s += t*t; }
    ((float*)(ws + S2_OFF))[o] = g2[o] / sqrtf(s);
  }
}

// ---- precompute 2: pack normalized weights into MFMA B-fragment order (bf16) ----
__global__ void pack_kernel(const float* __restrict__ v0, const float* __restrict__ v1,
                            const float* __restrict__ v2, char* __restrict__ ws){
  int i = blockIdx.x * 256 + threadIdx.x;
  const float* s0 = (const float*)(ws + S0_OFF);
  const float* s1 = (const float*)(ws + S1_OFF);
  const float* s2 = (const float*)(ws + S2_OFF);
  if (i < 24576){
    int j = i & 7, l = (i >> 3) & 63, q = i >> 9;
    int kt = q % 3, nt = q / 3;
    int k = kt*32 + (l >> 4)*8 + j, col = nt*16 + (l & 15);
    float v = (k < 71) ? v0[col*71 + k] * s0[col] : 0.f;
    ((unsigned short*)(ws + B0_OFF))[i] = f2bf(v);
  } else if (i < 90112){
    int e = i - 24576;
    int j = e & 7, l = (e >> 3) & 63, q = e >> 9;
    int kt = q & 7, nt = q >> 3;
    int k = kt*32 + (l >> 4)*8 + j, col = nt*16 + (l & 15);
    ((unsigned short*)(ws + B1_OFF))[e] = f2bf(v1[col*256 + k] * s1[col]);
  } else if (i < 155648){
    int e = i - 90112;
    int j = e & 7, l = (e >> 3) & 63, q = e >> 9;
    int kt = q & 7, nt = q >> 3;
    int k = kt*32 + (l >> 4)*8 + j, col = nt*16 + (l & 15);
    ((unsigned short*)(ws + B2_OFF))[e] = f2bf(v2[col*256 + k] * s2[col]);
  } else if (i < 155904){
    int k = i - 155648;
    ((float*)(ws + W2L_OFF))[k] = v2[256*256 + k] * s2[256];
  }
}

// ---- precompute 3: table f32 -> packed bf16x2 ----
__global__ void tconv_kernel(const float* __restrict__ table, char* __restrict__ ws, int total){
  int i = blockIdx.x * 256 + threadIdx.x;
  if (i < total){
    float2 v = ((const float2*)table)[i];
    ((unsigned*)(ws + TBF_OFF))[i] = ((unsigned)f2bf(v.x)) | (((unsigned)f2bf(v.y)) << 16);
  }
}

// ---- sort passes ----
__global__ void hist_kernel(const float* __restrict__ xin,
                            unsigned* __restrict__ hist, unsigned* __restrict__ keys){
  int i = blockIdx.x * 256 + threadIdx.x;
  float x0 = xin[i*3], x1 = xin[i*3+1], x2 = xin[i*3+2];
  unsigned cx = min(31u, (unsigned)(x0 * 32.f));
  unsigned cy = min(31u, (unsigned)(x1 * 32.f));
  unsigned cz = min(31u, (unsigned)(x2 * 32.f));
  unsigned k = morton5(cx, cy, cz);
  keys[i] = k;
  atomicAdd(&hist[k], 1u);
}

__global__ __launch_bounds__(1024) void scan_kernel(unsigned* __restrict__ hist){
  __shared__ unsigned sdata[1024];
  int t = threadIdx.x;
  unsigned loc[32];
  unsigned s = 0;
  #pragma unroll
  for (int k = 0; k < 32; k++){ loc[k] = hist[t*32 + k]; s += loc[k]; }
  sdata[t] = s;
  __syncthreads();
  for (int d = 1; d < 1024; d <<= 1){
    unsigned v = (t >= d) ? sdata[t - d] : 0u;
    __syncthreads();
    sdata[t] += v;
    __syncthreads();
  }
  unsigned run = (t == 0) ? 0u : sdata[t - 1];
  #pragma unroll
  for (int k = 0; k < 32; k++){ unsigned c = loc[k]; hist[t*32 + k] = run; run += c; }
}

__global__ void scatter_kernel(const unsigned* __restrict__ keys,
                               unsigned* __restrict__ hist, int* __restrict__ perm){
  int i = blockIdx.x * 256 + threadIdx.x;
  unsigned k = keys[i];
  unsigned r = atomicAdd(&hist[k], 1u);
  perm[r] = i;
}

// ============================================================================
// Fused v4: 4 tiles of 64 sorted points per block, software-pipelined —
// tile t+1's 32 gathers are issued right after tile t's features are
// consumed, hiding gather latency under 3 MFMA layers of tile t.
// ============================================================================
template<int USEBF>
__global__ __launch_bounds__(256, 3) void fused4(
    const float* __restrict__ xin, const float* __restrict__ table,
    char* __restrict__ ws, const int* __restrict__ perm,
    const float* __restrict__ b0, const float* __restrict__ b1, const float* __restrict__ b2,
    float* __restrict__ out, HashCfg cfg)
{
  __shared__ unsigned short buf[64 * 256];  // swizzled: elem(row,col) at col^((row&7)<<3)
  __shared__ float colsc[4][64];
  __shared__ int pids_sh[TILES][64];

  const int tid = threadIdx.x;
  const int p   = tid & 63;
  const int grp = tid >> 6;
  const int l   = tid & 63;
  const int lr  = l & 15;
  const int lh  = l >> 4;
  const int wv  = grp;
  // bijective XCD swizzle over 2048 blocks (8 * 256)
  const int lb  = (blockIdx.x & 7) * 256 + (blockIdx.x >> 3);
  const int base_idx = lb * (TILES * 64);

  const unsigned* __restrict__ tbf = (const unsigned*)(ws + TBF_OFF);
  const short8* B0p = (const short8*)(ws + B0_OFF);
  const short8* B1p = (const short8*)(ws + B1_OFF);
  const short8* B2p = (const short8*)(ws + B2_OFF);
  const float* w2l = (const float*)(ws + W2L_OFF);

  auto stB = [&](int row, int col, float v){
    buf[row*256 + (col ^ ((row & 7) << 3))] = f2bf(v);
  };
  auto ldB = [&](int row, int kb) -> short8 {
    return *(const short8*)&buf[row*256 + (kb ^ ((row & 7) << 3))];
  };

  if (grp == 0){
    #pragma unroll
    for (int t = 0; t < TILES; t++){
      int gi = base_idx + t*64 + p;
      pids_sh[t][p] = perm ? perm[gi] : gi;
    }
  }
  __syncthreads();

  // pipeline registers (filled by issue, consumed at next loop top)
  float xc0, xc1, xc2;               // x of the tile whose gathers are in flight
  float wxa[4], wya[4], wza[4];
  unsigned vb[4][8];
  float2   vf2[4][8];

  auto issue_tile = [&](int t){
    int pid = pids_sh[t][p];
    xc0 = xin[pid*3]; xc1 = xin[pid*3+1]; xc2 = xin[pid*3+2];
    #pragma unroll
    for (int ii = 0; ii < 4; ii++){
      int lev = grp*4 + ii;
      int res = cfg.res[lev];
      float scl = (float)(res - 1);
      float px = xc0*scl, py = xc1*scl, pz = xc2*scl;
      float fx = floorf(px), fy = floorf(py), fz = floorf(pz);
      wxa[ii] = px - fx; wya[ii] = py - fy; wza[ii] = pz - fz;
      unsigned cx0 = (unsigned)fx, cy0 = (unsigned)fy, cz0 = (unsigned)fz;
      unsigned r1 = (unsigned)(res + 1);
      bool hl = (cfg.hashed_mask >> lev) & 1;
      unsigned base = (unsigned)cfg.off[lev];
      #pragma unroll
      for (int c = 0; c < 8; c++){
        unsigned bx = (c >> 2) & 1, by = (c >> 1) & 1, bz = c & 1;
        unsigned cx = cx0 + bx, cy = cy0 + by, cz = cz0 + bz;
        unsigned hidx = hl ? ((cx ^ (cy * 2654435761u) ^ (cz * 805459861u)) & TMASK)
                           : (cx + cy * r1 + cz * r1 * r1);
        if (USEBF) vb[ii][c]  = tbf[base + hidx];
        else       vf2[ii][c] = *(const float2*)(table + (size_t)(base + hidx) * 2u);
      }
    }
  };

  issue_tile(0);

  for (int t = 0; t < TILES; t++){
    // ---- consume gathers(t): trilinear combine -> features in LDS ----
    #pragma unroll
    for (int ii = 0; ii < 4; ii++){
      int lev = grp*4 + ii;
      float wx = wxa[ii], wy = wya[ii], wz = wza[ii];
      float f0 = 0.f, f1 = 0.f;
      #pragma unroll
      for (int c = 0; c < 8; c++){
        unsigned bx = (c >> 2) & 1, by = (c >> 1) & 1, bz = c & 1;
        float w = (bx ? wx : 1.f - wx) * (by ? wy : 1.f - wy) * (bz ? wz : 1.f - wz);
        if (USEBF){
          unsigned u = vb[ii][c];
          f0 += w * __uint_as_float(u << 16);
          f1 += w * __uint_as_float(u & 0xffff0000u);
        } else {
          f0 += w * vf2[ii][c].x;
          f1 += w * vf2[ii][c].y;
        }
      }
      stB(p, 39 + 2*lev, f0);
      stB(p, 40 + 2*lev, f1);
    }
    // trig / input / K-pad (uses this tile's x, still in xc regs)
    if (grp < 3){
      float xv[3] = {xc0, xc1, xc2};
      #pragma unroll
      for (int fi = 0; fi < 2; fi++){
        int f = grp*2 + fi;
        float fr = (float)(1 << f);
        #pragma unroll
        for (int d = 0; d < 3; d++){
          float a = xv[d] * fr;
          stB(p, 3 + f*6 + d,     __sinf(a));
          stB(p, 3 + f*6 + 3 + d, __cosf(a));
        }
      }
    } else {
      stB(p, 0, xc0); stB(p, 1, xc1); stB(p, 2, xc2);
      #pragma unroll
      for (int c = 71; c < 96; c++)
        buf[p*256 + (c ^ ((p & 7) << 3))] = 0;
    }

    // ---- issue gathers for next tile: in flight across all 3 MFMA layers ----
    if (t + 1 < TILES) issue_tile(t + 1);
    __syncthreads();

    { // ----- layer 0 -----
      f32x4 acc[4][4];
      #pragma unroll
      for (int a = 0; a < 4; a++)
        #pragma unroll
        for (int b = 0; b < 4; b++) acc[a][b] = (f32x4){0.f,0.f,0.f,0.f};
      #pragma unroll
      for (int kt = 0; kt < 3; kt++){
        short8 af[4];
        #pragma unroll
        for (int mt = 0; mt < 4; mt++) af[mt] = ldB(mt*16 + lr, kt*32 + lh*8);
        #pragma unroll
        for (int nt = 0; nt < 4; nt++){
          short8 bf = B0p[((wv*4 + nt)*3 + kt)*64 + l];
          #pragma unroll
          for (int mt = 0; mt < 4; mt++)
            acc[mt][nt] = __builtin_amdgcn_mfma_f32_16x16x32_bf16(af[mt], bf, acc[mt][nt], 0, 0, 0);
        }
      }
      __syncthreads();
      float bb[4];
      #pragma unroll
      for (int nt = 0; nt < 4; nt++) bb[nt] = b0[wv*64 + nt*16 + lr];
      #pragma unroll
      for (int mt = 0; mt < 4; mt++)
        #pragma unroll
        for (int nt = 0; nt < 4; nt++){
          int c = wv*64 + nt*16 + lr;
          #pragma unroll
          for (int j = 0; j < 4; j++)
            stB(mt*16 + lh*4 + j, c, softplus100_fast(acc[mt][nt][j] + bb[nt]));
        }
    }
    __syncthreads();

    { // ----- layer 1 -----
      f32x4 acc[4][4];
      #pragma unroll
      for (int a = 0; a < 4; a++)
        #pragma unroll
        for (int b = 0; b < 4; b++) acc[a][b] = (f32x4){0.f,0.f,0.f,0.f};
      #pragma unroll
      for (int kt = 0; kt < 8; kt++){
        short8 af[4];
        #pragma unroll
        for (int mt = 0; mt < 4; mt++) af[mt] = ldB(mt*16 + lr, kt*32 + lh*8);
        #pragma unroll
        for (int nt = 0; nt < 4; nt++){
          short8 bf = B1p[((wv*4 + nt)*8 + kt)*64 + l];
          #pragma unroll
          for (int mt = 0; mt < 4; mt++)
            acc[mt][nt] = __builtin_amdgcn_mfma_f32_16x16x32_bf16(af[mt], bf, acc[mt][nt], 0, 0, 0);
        }
      }
      __syncthreads();
      float bb[4];
      #pragma unroll
      for (int nt = 0; nt < 4; nt++) bb[nt] = b1[wv*64 + nt*16 + lr];
      #pragma unroll
      for (int mt = 0; mt < 4; mt++)
        #pragma unroll
        for (int nt = 0; nt < 4; nt++){
          int c = wv*64 + nt*16 + lr;
          #pragma unroll
          for (int j = 0; j < 4; j++)
            stB(mt*16 + lh*4 + j, c, softplus100_fast(acc[mt][nt][j] + bb[nt]));
        }
    }
    __syncthreads();

    // last-col partials
    {
      float s = 0.f;
      #pragma unroll
      for (int q = 0; q < 8; q++){
        short8 h = ldB(l, wv*64 + q*8);
        #pragma unroll
        for (int j = 0; j < 8; j++)
          s += bf2f((unsigned short)h[j]) * w2l[wv*64 + q*8 + j];
      }
      colsc[wv][l] = s;
    }

    { // ----- layer 2 + direct scattered stores -----
      f32x4 acc[4][4];
      #pragma unroll
      for (int a = 0; a < 4; a++)
        #pragma unroll
        for (int b = 0; b < 4; b++) acc[a][b] = (f32x4){0.f,0.f,0.f,0.f};
      #pragma unroll
      for (int kt = 0; kt < 8; kt++){
        short8 af[4];
        #pragma unroll
        for (int mt = 0; mt < 4; mt++) af[mt] = ldB(mt*16 + lr, kt*32 + lh*8);
        #pragma unroll
        for (int nt = 0; nt < 4; nt++){
          short8 bf = B2p[((wv*4 + nt)*8 + kt)*64 + l];
          #pragma unroll
          for (int mt = 0; mt < 4; mt++)
            acc[mt][nt] = __builtin_amdgcn_mfma_f32_16x16x32_bf16(af[mt], bf, acc[mt][nt], 0, 0, 0);
        }
      }
      __syncthreads();   // colsc visible + all buf reads done (feat(t+1) writes follow)
      float bb[4];
      #pragma unroll
      for (int nt = 0; nt < 4; nt++) bb[nt] = b2[wv*64 + nt*16 + lr];
      int rowid[4][4];
      #pragma unroll
      for (int mt = 0; mt < 4; mt++)
        #pragma unroll
        for (int j = 0; j < 4; j++) rowid[mt][j] = pids_sh[t][mt*16 + lh*4 + j];
      #pragma unroll
      for (int mt = 0; mt < 4; mt++)
        #pragma unroll
        for (int nt = 0; nt < 4; nt++){
          int c = wv*64 + nt*16 + lr;
          #pragma unroll
          for (int j = 0; j < 4; j++)
            out[(size_t)rowid[mt][j]*257 + c] = acc[mt][nt][j] + bb[nt];
        }
      if (tid < 64)
        out[(size_t)pids_sh[t][tid]*257 + 256] =
          colsc[0][tid] + colsc[1][tid] + colsc[2][tid] + colsc[3][tid] + b2[256];
    }
    // no barrier needed here: next loop-top writes feat region of buf, which
    // was last READ by layer-0 MFMA of this tile (guarded by the barrier
    // after layer-2 MFMA above? no — guarded because every wave passed the
    // post-L2 barrier, and all buf reads precede it).
  }
}

// ---- host: replicate reference's double-precision level config exactly ----
static HashCfg make_cfg(){
  HashCfg c;
  double pls = exp2(log2(2048.0 / 16.0) / 15.0);
  long long off = 0;
  unsigned mask = 0;
  for (int l = 0; l < 16; l++){
    int r = (int)ceil(16.0 * pow(pls, (double)l));
    c.res[l] = r;
    c.off[l] = (int)off;
    double n3 = (double)(r + 1) * (double)(r + 1) * (double)(r + 1);
    long long size;
    if (n3 > 524288.0){ mask |= (1u << l); }
    size = (long long)(ceil(n3 / 8.0) * 8.0);
    if (size > 524288) size = 524288;
    off += size;
  }
  c.hashed_mask = mask;
  c.total = (int)off;
  return c;
}

extern "C" void kernel_launch(void* const* d_in, const int* in_sizes, int n_in,
                              void* d_out, int out_size, void* d_ws, size_t ws_size,
                              hipStream_t stream) {
  const float* x     = (const float*)d_in[0];
  const float* table = (const float*)d_in[1];
  const float* v0 = (const float*)d_in[2];
  const float* g0 = (const float*)d_in[3];
  const float* b0 = (const float*)d_in[4];
  const float* v1 = (const float*)d_in[5];
  const float* g1 = (const float*)d_in[6];
  const float* b1 = (const float*)d_in[7];
  const float* v2 = (const float*)d_in[8];
  const float* g2 = (const float*)d_in[9];
  const float* b2 = (const float*)d_in[10];
  float* out = (float*)d_out;
  char* ws = (char*)d_ws;

  HashCfg cfg = make_cfg();
  size_t tbf_bytes = (size_t)cfg.total * 4u;
  size_t hist_off  = (TBF_OFF + tbf_bytes + 255) & ~(size_t)255;
  size_t keys_off  = hist_off + (size_t)NCELLS * 4;
  size_t perm_off  = keys_off + (size_t)N_POINTS * 4;
  size_t need_sort = perm_off + (size_t)N_POINTS * 4;
  size_t need_bf   = TBF_OFF + tbf_bytes;

  hipLaunchKernelGGL(scale_kernel, dim3(4), dim3(256), 0, stream, v0, g0, v1, g1, v2, g2, ws);
  hipLaunchKernelGGL(pack_kernel, dim3(609), dim3(256), 0, stream, v0, v1, v2, ws);

  const int nblk = N_POINTS / (TILES * 64);   // 2048

  if (ws_size >= need_sort){
    unsigned* hist = (unsigned*)(ws + hist_off);
    unsigned* keys = (unsigned*)(ws + keys_off);
    int*      perm = (int*)(ws + perm_off);
    hipMemsetAsync(hist, 0, (size_t)NCELLS * 4, stream);
    hipLaunchKernelGGL(tconv_kernel, dim3((cfg.total + 255) / 256), dim3(256), 0, stream,
                       table, ws, cfg.total);
    hipLaunchKernelGGL(hist_kernel, dim3(N_POINTS / 256), dim3(256), 0, stream, x, hist, keys);
    hipLaunchKernelGGL(scan_kernel, dim3(1), dim3(1024), 0, stream, hist);
    hipLaunchKernelGGL(scatter_kernel, dim3(N_POINTS / 256), dim3(256), 0, stream, keys, hist, perm);
    hipLaunchKernelGGL((fused4<1>), dim3(nblk), dim3(256), 0, stream,
                       x, table, ws, perm, b0, b1, b2, out, cfg);
  } else if (ws_size >= need_bf){
    hipLaunchKernelGGL(tconv_kernel, dim3((cfg.total + 255) / 256), dim3(256), 0, stream,
                       table, ws, cfg.total);
    hipLaunchKernelGGL((fused4<1>), dim3(nblk), dim3(256), 0, stream,
                       x, table, ws, (const int*)nullptr, b0, b1, b2, out, cfg);
  } else {
    hipLaunchKernelGGL((fused4<0>), dim3(nblk), dim3(256), 0, stream,
                       x, table, ws, (const int*)nullptr, b0, b1, b2, out, cfg);
  }
}

// Round 7
// 943.719 us; speedup vs baseline: 2.3807x; 2.3807x over previous
//
#include <hip/hip_runtime.h>
#include <cmath>

typedef float f32x4 __attribute__((ext_vector_type(4)));
typedef short short8 __attribute__((ext_vector_type(8)));

#define N_POINTS 524288
#define TMASK 0x7FFFFu   // T_MAX-1, hashed levels all have size 2^19
#define NCELLS 32768     // 32^3 Morton cells

struct HashCfg { int res[16]; int off[16]; unsigned hashed_mask; int total; };

// ---- ws layout (bytes) ----
#define S0_OFF   0
#define S1_OFF   1024
#define S2_OFF   2048
#define W2L_OFF  3328
#define B0_OFF   4608
#define B1_OFF   (B0_OFF + 49152)
#define B2_OFF   (B1_OFF + 131072)
#define TBF_OFF  (B2_OFF + 131072)   // bf16x2 table copy (~24.5 MB); sort arrays after

__device__ inline unsigned short f2bf(float f){
  unsigned u = __float_as_uint(f);
  u = (u + 0x7FFFu + ((u >> 16) & 1u)) >> 16;
  return (unsigned short)u;
}
__device__ inline float bf2f(unsigned short h){
  return __uint_as_float(((unsigned)h) << 16);
}
__device__ inline float softplus100_fast(float x){
  float y = 100.f * x;
  return 0.01f * (fmaxf(y, 0.f) + __logf(1.f + __expf(-fabsf(y))));
}
__device__ inline unsigned morton5(unsigned cx, unsigned cy, unsigned cz){
  unsigned k = 0;
  #pragma unroll
  for (int b = 0; b < 5; b++){
    k |= ((cx >> b) & 1u) << (3*b)
       | ((cy >> b) & 1u) << (3*b + 1)
       | ((cz >> b) & 1u) << (3*b + 2);
  }
  return k;
}

// ---- precompute 1: weight-norm row scales ----
__global__ void scale_kernel(const float* __restrict__ v0, const float* __restrict__ g0,
                             const float* __restrict__ v1, const float* __restrict__ g1,
                             const float* __restrict__ v2, const float* __restrict__ g2,
                             char* __restrict__ ws){
  int r = blockIdx.x * 256 + threadIdx.x;
  if (r < 256){
    float s = 0.f;
    for (int k = 0; k < 71; k++){ float t = v0[r*71+k]; s += t*t; }
    ((float*)(ws + S0_OFF))[r] = g0[r] / sqrtf(s);
  } else if (r < 512){
    int o = r - 256; float s = 0.f;
    for (int k = 0; k < 256; k++){ float t = v1[o*256+k]; s += t*t; }
    ((float*)(ws + S1_OFF))[o] = g1[o] / sqrtf(s);
  } else if (r < 769){
    int o = r - 512; float s = 0.f;
    for (int k = 0; k < 256; k++){ float t = v2[o*256+k]; s += t*t; }
    ((float*)(ws + S2_OFF))[o] = g2[o] / sqrtf(s);
  }
}

// ---- precompute 2: pack normalized weights into MFMA B-fragment order (bf16) ----
__global__ void pack_kernel(const float* __restrict__ v0, const float* __restrict__ v1,
                            const float* __restrict__ v2, char* __restrict__ ws){
  int i = blockIdx.x * 256 + threadIdx.x;
  const float* s0 = (const float*)(ws + S0_OFF);
  const float* s1 = (const float*)(ws + S1_OFF);
  const float* s2 = (const float*)(ws + S2_OFF);
  if (i < 24576){
    int j = i & 7, l = (i >> 3) & 63, q = i >> 9;
    int kt = q % 3, nt = q / 3;
    int k = kt*32 + (l >> 4)*8 + j, col = nt*16 + (l & 15);
    float v = (k < 71) ? v0[col*71 + k] * s0[col] : 0.f;
    ((unsigned short*)(ws + B0_OFF))[i] = f2bf(v);
  } else if (i < 90112){
    int e = i - 24576;
    int j = e & 7, l = (e >> 3) & 63, q = e >> 9;
    int kt = q & 7, nt = q >> 3;
    int k = kt*32 + (l >> 4)*8 + j, col = nt*16 + (l & 15);
    ((unsigned short*)(ws + B1_OFF))[e] = f2bf(v1[col*256 + k] * s1[col]);
  } else if (i < 155648){
    int e = i - 90112;
    int j = e & 7, l = (e >> 3) & 63, q = e >> 9;
    int kt = q & 7, nt = q >> 3;
    int k = kt*32 + (l >> 4)*8 + j, col = nt*16 + (l & 15);
    ((unsigned short*)(ws + B2_OFF))[e] = f2bf(v2[col*256 + k] * s2[col]);
  } else if (i < 155904){
    int k = i - 155648;
    ((float*)(ws + W2L_OFF))[k] = v2[256*256 + k] * s2[256];
  }
}

// ---- precompute 3: table f32 -> packed bf16x2 ----
__global__ void tconv_kernel(const float* __restrict__ table, char* __restrict__ ws, int total){
  int i = blockIdx.x * 256 + threadIdx.x;
  if (i < total){
    float2 v = ((const float2*)table)[i];
    ((unsigned*)(ws + TBF_OFF))[i] = ((unsigned)f2bf(v.x)) | (((unsigned)f2bf(v.y)) << 16);
  }
}

// ---- sort passes ----
__global__ void hist_kernel(const float* __restrict__ xin,
                            unsigned* __restrict__ hist, unsigned* __restrict__ keys){
  int i = blockIdx.x * 256 + threadIdx.x;
  float x0 = xin[i*3], x1 = xin[i*3+1], x2 = xin[i*3+2];
  unsigned cx = min(31u, (unsigned)(x0 * 32.f));
  unsigned cy = min(31u, (unsigned)(x1 * 32.f));
  unsigned cz = min(31u, (unsigned)(x2 * 32.f));
  unsigned k = morton5(cx, cy, cz);
  keys[i] = k;
  atomicAdd(&hist[k], 1u);
}

__global__ __launch_bounds__(1024) void scan_kernel(unsigned* __restrict__ hist){
  __shared__ unsigned sdata[1024];
  int t = threadIdx.x;
  unsigned loc[32];
  unsigned s = 0;
  #pragma unroll
  for (int k = 0; k < 32; k++){ loc[k] = hist[t*32 + k]; s += loc[k]; }
  sdata[t] = s;
  __syncthreads();
  for (int d = 1; d < 1024; d <<= 1){
    unsigned v = (t >= d) ? sdata[t - d] : 0u;
    __syncthreads();
    sdata[t] += v;
    __syncthreads();
  }
  unsigned run = (t == 0) ? 0u : sdata[t - 1];
  #pragma unroll
  for (int k = 0; k < 32; k++){ unsigned c = loc[k]; hist[t*32 + k] = run; run += c; }
}

// scatter + build pre-permuted coordinate array sx[r*3..] = x[perm[r]*3..]
__global__ void scatter_kernel(const float* __restrict__ xin,
                               const unsigned* __restrict__ keys,
                               unsigned* __restrict__ hist, int* __restrict__ perm,
                               float* __restrict__ sx){
  int i = blockIdx.x * 256 + threadIdx.x;
  unsigned k = keys[i];
  unsigned r = atomicAdd(&hist[k], 1u);
  perm[r] = i;
  float x0 = xin[i*3], x1 = xin[i*3+1], x2 = xin[i*3+2];
  sx[r*3]   = x0;
  sx[r*3+1] = x1;
  sx[r*3+2] = x2;
}

// ============================================================================
// Fused v5: 32 sorted points per block, 4 waves, small LDS (17.5 KB) so 6-8
// blocks/CU interleave gather stalls against other blocks' MFMA/VALU phases.
// ============================================================================
template<int USEBF>
__global__ __launch_bounds__(256, 6) void fused5(
    const float* __restrict__ xin, const float* __restrict__ table,
    char* __restrict__ ws, const int* __restrict__ perm, const float* __restrict__ sx,
    const float* __restrict__ b0, const float* __restrict__ b1, const float* __restrict__ b2,
    float* __restrict__ out, HashCfg cfg)
{
  __shared__ unsigned short buf[32 * 256];  // swizzled: elem(row,col) at col^((row&7)<<3)
  __shared__ float colsc[8][32];
  __shared__ int pids_sh[32];

  const int tid = threadIdx.x;
  const int p2  = tid & 31;        // local point / row (32 per block)
  const int hf  = (tid >> 5) & 1;  // half-wave id
  const int grp = tid >> 6;        // wave id
  const int l   = tid & 63;
  const int lr  = l & 15;
  const int lh  = l >> 4;
  const int wv  = grp;
  // bijective XCD swizzle over 16384 blocks (8 * 2048)
  const int lb  = (blockIdx.x & 7) * 2048 + (blockIdx.x >> 3);
  const int base_idx = lb * 32;

  const unsigned* __restrict__ tbf = (const unsigned*)(ws + TBF_OFF);
  const short8* B0p = (const short8*)(ws + B0_OFF);
  const short8* B1p = (const short8*)(ws + B1_OFF);
  const short8* B2p = (const short8*)(ws + B2_OFF);
  const float* w2l = (const float*)(ws + W2L_OFF);

  auto stB = [&](int row, int col, float v){
    buf[row*256 + (col ^ ((row & 7) << 3))] = f2bf(v);
  };
  auto ldB = [&](int row, int kb) -> short8 {
    return *(const short8*)&buf[row*256 + (kb ^ ((row & 7) << 3))];
  };

  if (tid < 32) pids_sh[p2] = perm ? perm[base_idx + p2] : (base_idx + p2);

  // coordinates: pre-permuted contiguous reads when sorted, else direct
  float xc0, xc1, xc2;
  if (sx){
    xc0 = sx[(base_idx + p2)*3];
    xc1 = sx[(base_idx + p2)*3 + 1];
    xc2 = sx[(base_idx + p2)*3 + 2];
  } else {
    int pid = base_idx + p2;
    xc0 = xin[pid*3]; xc1 = xin[pid*3+1]; xc2 = xin[pid*3+2];
  }

  // ---------- phase E: 2 levels per thread, issue 16 gathers then trig ----------
  {
    float wxa[2], wya[2], wza[2];
    unsigned vb[2][8];
    float2   vf2[2][8];

    #pragma unroll
    for (int ii = 0; ii < 2; ii++){
      int lev = hf*8 + grp*2 + ii;
      int res = cfg.res[lev];
      float scl = (float)(res - 1);
      float px = xc0*scl, py = xc1*scl, pz = xc2*scl;
      float fx = floorf(px), fy = floorf(py), fz = floorf(pz);
      wxa[ii] = px - fx; wya[ii] = py - fy; wza[ii] = pz - fz;
      unsigned cx0 = (unsigned)fx, cy0 = (unsigned)fy, cz0 = (unsigned)fz;
      unsigned r1 = (unsigned)(res + 1);
      bool hl = (cfg.hashed_mask >> lev) & 1;
      unsigned base = (unsigned)cfg.off[lev];
      #pragma unroll
      for (int c = 0; c < 8; c++){
        unsigned bx = (c >> 2) & 1, by = (c >> 1) & 1, bz = c & 1;
        unsigned cx = cx0 + bx, cy = cy0 + by, cz = cz0 + bz;
        unsigned hidx = hl ? ((cx ^ (cy * 2654435761u) ^ (cz * 805459861u)) & TMASK)
                           : (cx + cy * r1 + cz * r1 * r1);
        if constexpr (USEBF) vb[ii][c]  = tbf[base + hidx];
        else                 vf2[ii][c] = *(const float2*)(table + (size_t)(base + hidx) * 2u);
      }
    }

    // trig / input / K-pad (8 roles per point) overlaps gather latency
    {
      int role = tid >> 5;   // 0..7
      if (role < 6){
        float fr = (float)(1 << role);
        float xv[3] = {xc0, xc1, xc2};
        #pragma unroll
        for (int d = 0; d < 3; d++){
          float a = xv[d] * fr;
          stB(p2, 3 + role*6 + d,     __sinf(a));
          stB(p2, 3 + role*6 + 3 + d, __cosf(a));
        }
      } else if (role == 6){
        stB(p2, 0, xc0); stB(p2, 1, xc1); stB(p2, 2, xc2);
      } else {
        #pragma unroll
        for (int c = 71; c < 96; c++)
          buf[p2*256 + (c ^ ((p2 & 7) << 3))] = 0;
      }
    }

    // consume
    #pragma unroll
    for (int ii = 0; ii < 2; ii++){
      int lev = hf*8 + grp*2 + ii;
      float wx = wxa[ii], wy = wya[ii], wz = wza[ii];
      float f0 = 0.f, f1 = 0.f;
      #pragma unroll
      for (int c = 0; c < 8; c++){
        unsigned bx = (c >> 2) & 1, by = (c >> 1) & 1, bz = c & 1;
        float w = (bx ? wx : 1.f - wx) * (by ? wy : 1.f - wy) * (bz ? wz : 1.f - wz);
        if constexpr (USEBF){
          unsigned u = vb[ii][c];
          f0 += w * __uint_as_float(u << 16);
          f1 += w * __uint_as_float(u & 0xffff0000u);
        } else {
          f0 += w * vf2[ii][c].x;
          f1 += w * vf2[ii][c].y;
        }
      }
      stB(p2, 39 + 2*lev, f0);
      stB(p2, 40 + 2*lev, f1);
    }
  }
  __syncthreads();

  // ---------- MFMA phases: rows 0..31 (mt 0..1), wave owns cols wv*64..+63 ----------
  { // ----- layer 0 -----
    f32x4 acc[2][4];
    #pragma unroll
    for (int a = 0; a < 2; a++)
      #pragma unroll
      for (int b = 0; b < 4; b++) acc[a][b] = (f32x4){0.f,0.f,0.f,0.f};
    #pragma unroll
    for (int kt = 0; kt < 3; kt++){
      short8 af[2];
      #pragma unroll
      for (int mt = 0; mt < 2; mt++) af[mt] = ldB(mt*16 + lr, kt*32 + lh*8);
      #pragma unroll
      for (int nt = 0; nt < 4; nt++){
        short8 bf = B0p[((wv*4 + nt)*3 + kt)*64 + l];
        #pragma unroll
        for (int mt = 0; mt < 2; mt++)
          acc[mt][nt] = __builtin_amdgcn_mfma_f32_16x16x32_bf16(af[mt], bf, acc[mt][nt], 0, 0, 0);
      }
    }
    __syncthreads();
    float bb[4];
    #pragma unroll
    for (int nt = 0; nt < 4; nt++) bb[nt] = b0[wv*64 + nt*16 + lr];
    #pragma unroll
    for (int mt = 0; mt < 2; mt++)
      #pragma unroll
      for (int nt = 0; nt < 4; nt++){
        int c = wv*64 + nt*16 + lr;
        #pragma unroll
        for (int j = 0; j < 4; j++)
          stB(mt*16 + lh*4 + j, c, softplus100_fast(acc[mt][nt][j] + bb[nt]));
      }
  }
  __syncthreads();

  { // ----- layer 1 -----
    f32x4 acc[2][4];
    #pragma unroll
    for (int a = 0; a < 2; a++)
      #pragma unroll
      for (int b = 0; b < 4; b++) acc[a][b] = (f32x4){0.f,0.f,0.f,0.f};
    #pragma unroll
    for (int kt = 0; kt < 8; kt++){
      short8 af[2];
      #pragma unroll
      for (int mt = 0; mt < 2; mt++) af[mt] = ldB(mt*16 + lr, kt*32 + lh*8);
      #pragma unroll
      for (int nt = 0; nt < 4; nt++){
        short8 bf = B1p[((wv*4 + nt)*8 + kt)*64 + l];
        #pragma unroll
        for (int mt = 0; mt < 2; mt++)
          acc[mt][nt] = __builtin_amdgcn_mfma_f32_16x16x32_bf16(af[mt], bf, acc[mt][nt], 0, 0, 0);
      }
    }
    __syncthreads();
    float bb[4];
    #pragma unroll
    for (int nt = 0; nt < 4; nt++) bb[nt] = b1[wv*64 + nt*16 + lr];
    #pragma unroll
    for (int mt = 0; mt < 2; mt++)
      #pragma unroll
      for (int nt = 0; nt < 4; nt++){
        int c = wv*64 + nt*16 + lr;
        #pragma unroll
        for (int j = 0; j < 4; j++)
          stB(mt*16 + lh*4 + j, c, softplus100_fast(acc[mt][nt][j] + bb[nt]));
      }
  }
  __syncthreads();  // h2 visible

  // last-col partials: thread handles row p2, cols (tid>>5)*32 .. +31
  {
    int ch = tid >> 5;   // 0..7
    float s = 0.f;
    #pragma unroll
    for (int q = 0; q < 4; q++){
      short8 h = ldB(p2, ch*32 + q*8);
      #pragma unroll
      for (int j = 0; j < 8; j++)
        s += bf2f((unsigned short)h[j]) * w2l[ch*32 + q*8 + j];
    }
    colsc[ch][p2] = s;
  }

  { // ----- layer 2 + nontemporal scattered stores -----
    f32x4 acc[2][4];
    #pragma unroll
    for (int a = 0; a < 2; a++)
      #pragma unroll
      for (int b = 0; b < 4; b++) acc[a][b] = (f32x4){0.f,0.f,0.f,0.f};
    #pragma unroll
    for (int kt = 0; kt < 8; kt++){
      short8 af[2];
      #pragma unroll
      for (int mt = 0; mt < 2; mt++) af[mt] = ldB(mt*16 + lr, kt*32 + lh*8);
      #pragma unroll
      for (int nt = 0; nt < 4; nt++){
        short8 bf = B2p[((wv*4 + nt)*8 + kt)*64 + l];
        #pragma unroll
        for (int mt = 0; mt < 2; mt++)
          acc[mt][nt] = __builtin_amdgcn_mfma_f32_16x16x32_bf16(af[mt], bf, acc[mt][nt], 0, 0, 0);
      }
    }
    __syncthreads();   // colsc partials visible
    float bb[4];
    #pragma unroll
    for (int nt = 0; nt < 4; nt++) bb[nt] = b2[wv*64 + nt*16 + lr];
    int rowid[2][4];
    #pragma unroll
    for (int mt = 0; mt < 2; mt++)
      #pragma unroll
      for (int j = 0; j < 4; j++) rowid[mt][j] = pids_sh[mt*16 + lh*4 + j];
    #pragma unroll
    for (int mt = 0; mt < 2; mt++)
      #pragma unroll
      for (int nt = 0; nt < 4; nt++){
        int c = wv*64 + nt*16 + lr;
        #pragma unroll
        for (int j = 0; j < 4; j++)
          __builtin_nontemporal_store(acc[mt][nt][j] + bb[nt],
                                      &out[(size_t)rowid[mt][j]*257 + c]);
      }
    if (tid < 32){
      float s = colsc[0][p2] + colsc[1][p2] + colsc[2][p2] + colsc[3][p2]
              + colsc[4][p2] + colsc[5][p2] + colsc[6][p2] + colsc[7][p2] + b2[256];
      __builtin_nontemporal_store(s, &out[(size_t)pids_sh[p2]*257 + 256]);
    }
  }
}

// ---- host: replicate reference's double-precision level config exactly ----
static HashCfg make_cfg(){
  HashCfg c;
  double pls = exp2(log2(2048.0 / 16.0) / 15.0);
  long long off = 0;
  unsigned mask = 0;
  for (int l = 0; l < 16; l++){
    int r = (int)ceil(16.0 * pow(pls, (double)l));
    c.res[l] = r;
    c.off[l] = (int)off;
    double n3 = (double)(r + 1) * (double)(r + 1) * (double)(r + 1);
    long long size;
    if (n3 > 524288.0){ mask |= (1u << l); }
    size = (long long)(ceil(n3 / 8.0) * 8.0);
    if (size > 524288) size = 524288;
    off += size;
  }
  c.hashed_mask = mask;
  c.total = (int)off;
  return c;
}

extern "C" void kernel_launch(void* const* d_in, const int* in_sizes, int n_in,
                              void* d_out, int out_size, void* d_ws, size_t ws_size,
                              hipStream_t stream) {
  const float* x     = (const float*)d_in[0];
  const float* table = (const float*)d_in[1];
  const float* v0 = (const float*)d_in[2];
  const float* g0 = (const float*)d_in[3];
  const float* b0 = (const float*)d_in[4];
  const float* v1 = (const float*)d_in[5];
  const float* g1 = (const float*)d_in[6];
  const float* b1 = (const float*)d_in[7];
  const float* v2 = (const float*)d_in[8];
  const float* g2 = (const float*)d_in[9];
  const float* b2 = (const float*)d_in[10];
  float* out = (float*)d_out;
  char* ws = (char*)d_ws;

  HashCfg cfg = make_cfg();
  size_t tbf_bytes = (size_t)cfg.total * 4u;
  size_t hist_off  = (TBF_OFF + tbf_bytes + 255) & ~(size_t)255;
  size_t keys_off  = hist_off + (size_t)NCELLS * 4;
  size_t perm_off  = keys_off + (size_t)N_POINTS * 4;
  size_t sx_off    = perm_off + (size_t)N_POINTS * 4;
  size_t need_sort = sx_off + (size_t)N_POINTS * 12;
  size_t need_bf   = TBF_OFF + tbf_bytes;

  hipLaunchKernelGGL(scale_kernel, dim3(4), dim3(256), 0, stream, v0, g0, v1, g1, v2, g2, ws);
  hipLaunchKernelGGL(pack_kernel, dim3(609), dim3(256), 0, stream, v0, v1, v2, ws);

  const int nblk = N_POINTS / 32;   // 16384

  if (ws_size >= need_sort){
    unsigned* hist = (unsigned*)(ws + hist_off);
    unsigned* keys = (unsigned*)(ws + keys_off);
    int*      perm = (int*)(ws + perm_off);
    float*    sx   = (float*)(ws + sx_off);
    hipMemsetAsync(hist, 0, (size_t)NCELLS * 4, stream);
    hipLaunchKernelGGL(tconv_kernel, dim3((cfg.total + 255) / 256), dim3(256), 0, stream,
                       table, ws, cfg.total);
    hipLaunchKernelGGL(hist_kernel, dim3(N_POINTS / 256), dim3(256), 0, stream, x, hist, keys);
    hipLaunchKernelGGL(scan_kernel, dim3(1), dim3(1024), 0, stream, hist);
    hipLaunchKernelGGL(scatter_kernel, dim3(N_POINTS / 256), dim3(256), 0, stream,
                       x, keys, hist, perm, sx);
    hipLaunchKernelGGL((fused5<1>), dim3(nblk), dim3(256), 0, stream,
                       x, table, ws, perm, sx, b0, b1, b2, out, cfg);
  } else if (ws_size >= need_bf){
    hipLaunchKernelGGL(tconv_kernel, dim3((cfg.total + 255) / 256), dim3(256), 0, stream,
                       table, ws, cfg.total);
    hipLaunchKernelGGL((fused5<1>), dim3(nblk), dim3(256), 0, stream,
                       x, table, ws, (const int*)nullptr, (const float*)nullptr,
                       b0, b1, b2, out, cfg);
  } else {
    hipLaunchKernelGGL((fused5<0>), dim3(nblk), dim3(256), 0, stream,
                       x, table, ws, (const int*)nullptr, (const float*)nullptr,
                       b0, b1, b2, out, cfg);
  }
}